// Round 7
// baseline (548.396 us; speedup 1.0000x reference)
//
#include <hip/hip_runtime.h>
#include <hip/hip_cooperative_groups.h>

namespace cg = cooperative_groups;

#define N_NODES 100000
#define N_EDGES 1600000
#define D 64
#define N_BBOX 4096
#define CAP 64       // per-node slot capacity; deg ~ Poisson(16), P(>=64) ~ 1e-20
#define NBITW 3136   // words for N_NODES bits, padded
#define SLICE 12500  // N_NODES / 8 XCD slices
#define NBLK_A 6250  // N_EDGES / 256 exactly
#define SEGCAP 96    // unfiltered Binom(256,1/8): mean 32, 96 = +12 sigma
#define NTILE1 (N_NODES / 16)  // 6250
#define NTILE2 (N_BBOX / 16)   // 256
#define TPB1 2                 // tiles per gd1 virtual block

typedef short bf16x8 __attribute__((ext_vector_type(8)));
typedef float f32x4 __attribute__((ext_vector_type(4)));

__device__ __forceinline__ int bperm(int srclane, int v) {
  return __builtin_amdgcn_ds_bpermute(srclane << 2, v);
}
__device__ __forceinline__ float lrelu(float v) {
  return fmaxf(v, 0.01f * v);  // neg_slope 0.01 > 0
}
__device__ __forceinline__ bool testbit(const unsigned* bits, int i) {
  return (bits[i >> 5] >> (i & 31)) & 1u;
}
__device__ __forceinline__ short f2bf(float f) {  // RNE fp32 -> bf16
  unsigned u = __float_as_uint(f);
  u += 0x7FFFu + ((u >> 16) & 1u);
  return (short)(u >> 16);
}

// ---- wave-cooperative gather-sum (round-3 verified): 4-deep batches,
// wave-uniform skip of dead sub-batches. On exit accf[i] of lane (g=0,c)
// holds element c*8+i of the row-sum, replicated across 8 groups.
__device__ __forceinline__ void gather_rows(const uint4* __restrict__ rows,
                                            const int* __restrict__ slots,
                                            int node, int n, int lane,
                                            float accf[8]) {
  const int g = lane >> 3, c = lane & 7;
  const int myslot = (lane < n) ? slots[(size_t)node * CAP + lane] : 0;
#pragma unroll
  for (int i = 0; i < 8; i++) accf[i] = 0.f;
  for (int e0 = 0; e0 < n; e0 += 32) {
    const int rem = n - e0;  // wave-uniform
    int idx[4], s[4];
    uint4 v[4];
#pragma unroll
    for (int u = 0; u < 4; u++)
      if (u * 8 < rem) {
        idx[u] = e0 + u * 8 + g;
        s[u] = bperm(idx[u], myslot);
      }
#pragma unroll
    for (int u = 0; u < 4; u++)
      if (u * 8 < rem) {
        v[u] = make_uint4(0u, 0u, 0u, 0u);
        if (idx[u] < n) v[u] = rows[(size_t)s[u] * 8 + c];
      }
#pragma unroll
    for (int u = 0; u < 4; u++)
      if (u * 8 < rem) {
        accf[0] += __uint_as_float(v[u].x << 16);
        accf[1] += __uint_as_float(v[u].x & 0xFFFF0000u);
        accf[2] += __uint_as_float(v[u].y << 16);
        accf[3] += __uint_as_float(v[u].y & 0xFFFF0000u);
        accf[4] += __uint_as_float(v[u].z << 16);
        accf[5] += __uint_as_float(v[u].z & 0xFFFF0000u);
        accf[6] += __uint_as_float(v[u].w << 16);
        accf[7] += __uint_as_float(v[u].w & 0xFFFF0000u);
      }
  }
#pragma unroll
  for (int off = 8; off < 64; off <<= 1)
#pragma unroll
    for (int i = 0; i < 8; i++) accf[i] += __shfl_xor(accf[i], off);
}

// ================= single cooperative mega-kernel =================
// Phases: A zero+xprep+wfpack | B bbox mark | C scan | D scatterB |
//         E gd1 (layer1 gather+MFMA) | F gd2 (layer2, bbox rows).
// 5 grid.sync()s replace 6 kernel launches + 1 memset. Every phase is
// grid-stride -> correct for ANY grid size (launcher sizes via occupancy API).
__global__ __launch_bounds__(256, 4) void mega_kernel(
    const float4* __restrict__ x4, const int* __restrict__ bbox,
    const int* __restrict__ src, const int* __restrict__ dst,
    const float* __restrict__ W1rel, const float* __restrict__ b1,
    const float* __restrict__ W1root, const float* __restrict__ W2rel,
    const float* __restrict__ b2, const float* __restrict__ W2root,
    unsigned* __restrict__ is_bbox_bits, unsigned* __restrict__ needed_bits,
    int* __restrict__ cnt, int* __restrict__ qcnt, int* __restrict__ qseg,
    int* __restrict__ slots, short* xb, short* hb,
    short* __restrict__ wf, float* __restrict__ out) {
  cg::grid_group grid = cg::this_grid();
  __shared__ __align__(16) char smem[4608];  // union: scan 3104 | E 4608 | F 2368
  const int t = threadIdx.x;
  const int lane = t & 63;
  const int blk = blockIdx.x;
  const int nb = gridDim.x;  // multiple of 8 (launcher guarantees)
  const int gtid = blk * 256 + t;
  const int gstride = nb * 256;

  // ---------- phase A: zero bitmasks+cnt, x->bf16, weight-frag pack ----------
  for (int i = gtid; i < 2 * NBITW; i += gstride) {
    if (i < NBITW) is_bbox_bits[i] = 0u;
    else needed_bits[i - NBITW] = 0u;
  }
  for (int i = gtid; i < N_NODES; i += gstride) cnt[i] = 0;
  for (int i = gtid; i < N_NODES * 8; i += gstride) {
    const float4 a = x4[i * 2], b = x4[i * 2 + 1];
    bf16x8 r;
    r[0] = f2bf(a.x); r[1] = f2bf(a.y); r[2] = f2bf(a.z); r[3] = f2bf(a.w);
    r[4] = f2bf(b.x); r[5] = f2bf(b.y); r[6] = f2bf(b.z); r[7] = f2bf(b.w);
    ((bf16x8*)xb)[i] = r;
  }
  for (int t2 = gtid; t2 < 4 * 4096; t2 += gstride) {
    const int layer = t2 >> 13;          // 0: W1, 1: W2
    const int r = t2 & 8191;
    const int m = r >> 12;               // 0: rel, 1: root
    const int e = r & 4095;
    const int kh = e >> 11, quad = (e >> 9) & 3;
    const int col = (e >> 3) & 63, ii = e & 7;
    const int k = kh * 32 + quad * 8 + ii;
    const float* W = layer ? (m ? W2root : W2rel) : (m ? W1root : W1rel);
    wf[t2] = f2bf(W[k * 64 + col]);
  }
  grid.sync();

  // ---------- phase B: bbox marking (needs zeroed masks) ----------
  for (int i = gtid; i < N_BBOX; i += gstride) {
    const int n = bbox[i];
    const unsigned m = 1u << (n & 31);
    atomicOr(&is_bbox_bits[n >> 5], m);
    atomicOr(&needed_bits[n >> 5], m);
  }
  grid.sync();

  // ---------- phase C: edge scan (mark needed + block-segment binning) ----------
  {
    int* lcnt = (int*)smem;
    int* lbuf = lcnt + 8;
    const int niter = (NBLK_A + nb - 1) / nb;  // uniform across blocks
    for (int it = 0; it < niter; it++) {
      const int bseg = blk + it * nb;          // block-uniform
      const bool act = bseg < NBLK_A;
      if (t < 8) lcnt[t] = 0;
      __syncthreads();
      if (act) {
        const int e = bseg * 256 + t;
        const int d = dst[e];
        const int s = src[e];
        if (testbit(is_bbox_bits, d)) {
          atomicOr(&needed_bits[s >> 5], 1u << (s & 31));
        }
        const int q = d / SLICE;
        const int pv = s | ((d - q * SLICE) << 17);
#pragma unroll
        for (int qq = 0; qq < 8; qq++) {  // all 64 lanes active (act uniform)
          const unsigned long long mask = __ballot(q == qq);
          if (!mask) continue;
          const int nq = __popcll(mask);
          const int leader = (int)__builtin_ctzll(mask);
          int base = 0;
          if (lane == leader) base = atomicAdd(&lcnt[qq], nq);
          base = __builtin_amdgcn_readlane(base, leader);
          if (q == qq) {
            const int p = base + __popcll(mask & ((1ull << lane) - 1ull));
            if (p < SEGCAP) lbuf[qq * SEGCAP + p] = pv;
          }
        }
      }
      __syncthreads();
      if (act) {
        const size_t segbase = (size_t)bseg * 8;
        if (t < 8) qcnt[segbase + t] = (lcnt[t] > SEGCAP) ? SEGCAP : lcnt[t];
        for (int i = t; i < 8 * SEGCAP; i += 256) {
          const int q2 = i / SEGCAP, p2 = i - q2 * SEGCAP;
          if (p2 < lcnt[q2]) qseg[(segbase + q2) * SEGCAP + p2] = lbuf[i];
        }
      }
      __syncthreads();  // lcnt/lbuf reused next iteration
    }
  }
  grid.sync();

  // ---------- phase D: per-slice scatter + needed filter ----------
  {
    const int sl = blk & 7;
    const int bidx = blk >> 3;
    const int nblk2 = nb >> 3;
    const int base_node = sl * SLICE;
    const int sub = t >> 4;
    const int pp = t & 15;
    for (int b0 = bidx * 16; b0 < NBLK_A; b0 += nblk2 * 16) {
      const int b = b0 + sub;
      if (b >= NBLK_A) continue;
      const int n = qcnt[(size_t)b * 8 + sl];
      const int* seg = qseg + ((size_t)b * 8 + sl) * SEGCAP;
      for (int p = pp; p < n; p += 16) {
        const int pv = seg[p];
        const int d = base_node + (pv >> 17);
        if (!testbit(needed_bits, d)) continue;  // ~50% discard
        const int pos = atomicAdd(&cnt[d], 1);
        if (pos < CAP) slots[(size_t)d * CAP + pos] = pv & 0x1FFFF;
      }
    }
  }
  grid.sync();

  // ---------- phase E: layer-1 gather -> LDS -> MFMA -> hb ----------
  {
    const int wid = t >> 6;
    const int cn = lane & 15, quad = lane >> 4;
    const int col = wid * 16 + cn;
    short* aggt = (short*)smem;  // [TPB1][16][72]
    const uint4* xb4 = (const uint4*)xb;
    const bf16x8* wfv = (const bf16x8*)wf;
    bf16x8 brel[2], broot[2];
#pragma unroll
    for (int kh = 0; kh < 2; kh++) {
      brel[kh] = wfv[(kh * 4 + quad) * 64 + col];
      broot[kh] = wfv[((2 + kh) * 4 + quad) * 64 + col];
    }
    const float bj = b1[col];

    for (int vb = blk; vb < NTILE1 / TPB1; vb += nb) {
      const int tile0 = vb * TPB1;
#pragma unroll
      for (int tt = 0; tt < TPB1; tt++) {
        const int node0 = (tile0 + tt) * 16;
#pragma unroll
        for (int r4 = 0; r4 < 4; r4++) {
          const int row = wid * 4 + r4;
          const int node = node0 + row;
          int n = cnt[node];
          n = (n > CAP) ? CAP : n;
          short* dstp = aggt + (tt * 16 + row) * 72;
          if (n == 0) {  // non-needed (filtered) or deg-0: zero row
            if (lane < 8) {
              bf16x8 z = {0, 0, 0, 0, 0, 0, 0, 0};
              *(bf16x8*)(dstp + lane * 8) = z;
            }
            continue;
          }
          float accf[8];
          gather_rows(xb4, slots, node, n, lane, accf);
          if (lane < 8) {
            bf16x8 r;
#pragma unroll
            for (int i = 0; i < 8; i++) r[i] = f2bf(accf[i]);
            *(bf16x8*)(dstp + lane * 8) = r;
          }
        }
      }
      __syncthreads();
#pragma unroll
      for (int tt = 0; tt < TPB1; tt++) {
        const int node0 = (tile0 + tt) * 16;
        const int mrow = node0 + cn;
        const bool ndrow = testbit(needed_bits, mrow);
        f32x4 acc = {};
#pragma unroll
        for (int kh = 0; kh < 2; kh++) {
          const bf16x8 a_agg =
              *(const bf16x8*)(aggt + (tt * 16 + cn) * 72 + kh * 32 + quad * 8);
          bf16x8 a_x = {0, 0, 0, 0, 0, 0, 0, 0};
          if (ndrow)
            a_x = *(const bf16x8*)(xb + (size_t)mrow * D + kh * 32 + quad * 8);
          acc = __builtin_amdgcn_mfma_f32_16x16x32_bf16(a_agg, brel[kh], acc, 0, 0, 0);
          acc = __builtin_amdgcn_mfma_f32_16x16x32_bf16(a_x, broot[kh], acc, 0, 0, 0);
        }
#pragma unroll
        for (int r = 0; r < 4; r++) {
          const int row = quad * 4 + r;
          if (testbit(needed_bits, node0 + row))
            hb[(size_t)(node0 + row) * D + col] = f2bf(lrelu(acc[r] + bj));
        }
      }
      __syncthreads();  // aggt reused next virtual block
    }
  }
  grid.sync();

  // ---------- phase F: layer-2 for bbox rows (grid-strided tiles) ----------
  {
    const int wid = t >> 6;
    const int cn = lane & 15, quad = lane >> 4;
    const int col = wid * 16 + cn;
    short* aggt2 = (short*)smem;              // [16][72] = 2304 B
    int* nodes_s = (int*)(smem + 2304);       // 64 B
    const uint4* hb4 = (const uint4*)hb;
    const bf16x8* wfv = (const bf16x8*)(wf + 8192);
    bf16x8 brel[2], broot[2];
#pragma unroll
    for (int kh = 0; kh < 2; kh++) {
      brel[kh] = wfv[(kh * 4 + quad) * 64 + col];
      broot[kh] = wfv[((2 + kh) * 4 + quad) * 64 + col];
    }
    const float bj = b2[col];

    for (int vb = blk; vb < NTILE2; vb += nb) {
      const int t0 = vb * 16;
      if (t < 16) nodes_s[t] = bbox[t0 + t];
      __syncthreads();

#pragma unroll
      for (int r4 = 0; r4 < 4; r4++) {
        const int row = wid * 4 + r4;
        const int node = nodes_s[row];
        int n = cnt[node];
        n = (n > CAP) ? CAP : n;
        if (n == 0) {
          if (lane < 8) {
            bf16x8 z = {0, 0, 0, 0, 0, 0, 0, 0};
            *(bf16x8*)(aggt2 + row * 72 + lane * 8) = z;
          }
          continue;
        }
        float accf[8];
        gather_rows(hb4, slots, node, n, lane, accf);
        if (lane < 8) {
          bf16x8 r;
#pragma unroll
          for (int i = 0; i < 8; i++) r[i] = f2bf(accf[i]);
          *(bf16x8*)(aggt2 + row * 72 + lane * 8) = r;
        }
      }
      __syncthreads();

      const int rnode = nodes_s[cn];  // root row for A[m=cn]
      f32x4 acc = {};
#pragma unroll
      for (int kh = 0; kh < 2; kh++) {
        const bf16x8 a_agg = *(const bf16x8*)(aggt2 + cn * 72 + kh * 32 + quad * 8);
        const bf16x8 a_h =
            *(const bf16x8*)(hb + (size_t)rnode * D + kh * 32 + quad * 8);
        acc = __builtin_amdgcn_mfma_f32_16x16x32_bf16(a_agg, brel[kh], acc, 0, 0, 0);
        acc = __builtin_amdgcn_mfma_f32_16x16x32_bf16(a_h, broot[kh], acc, 0, 0, 0);
      }
#pragma unroll
      for (int r = 0; r < 4; r++) {
        const int row = quad * 4 + r;
        out[(size_t)(t0 + row) * D + col] = lrelu(acc[r] + bj);
      }
      __syncthreads();  // aggt2/nodes_s reused next tile
    }
  }
}

// ---------------- launch ----------------

extern "C" void kernel_launch(void* const* d_in, const int* in_sizes, int n_in,
                              void* d_out, int out_size, void* d_ws, size_t ws_size,
                              hipStream_t stream) {
  const float4* x4 = (const float4*)d_in[0];
  const int* ei = (const int*)d_in[1];
  const int* src = ei;
  const int* dst = ei + N_EDGES;
  const int* bbox = (const int*)d_in[2];
  const float* W1rel = (const float*)d_in[3];
  const float* b1 = (const float*)d_in[4];
  const float* W1root = (const float*)d_in[5];
  const float* W2rel = (const float*)d_in[6];
  const float* b2 = (const float*)d_in[7];
  const float* W2root = (const float*)d_in[8];
  float* out = (float*)d_out;

  char* ws = (char*)d_ws;
  size_t off = 0;
  auto alloc = [&](size_t bytes) -> char* {
    char* p = ws + off;
    off = (off + bytes + 511) & ~(size_t)511;
    return p;
  };
  unsigned* is_bbox_bits = (unsigned*)alloc(NBITW * sizeof(unsigned));
  unsigned* needed_bits = (unsigned*)alloc(NBITW * sizeof(unsigned));
  int* cnt = (int*)alloc(N_NODES * sizeof(int));
  int* qcnt = (int*)alloc((size_t)NBLK_A * 8 * sizeof(int));              // 200 KB
  int* qseg = (int*)alloc((size_t)NBLK_A * 8 * SEGCAP * sizeof(int));     // 19.2 MB
  int* slots = (int*)alloc((size_t)N_NODES * CAP * sizeof(int));          // 25.6 MB
  short* xb = (short*)alloc((size_t)N_NODES * D * sizeof(short));         // 12.8 MB
  short* hb = (short*)alloc((size_t)N_NODES * D * sizeof(short));         // 12.8 MB
  short* wf = (short*)alloc((size_t)4 * 4096 * sizeof(short));            // 32 KB

  // Occupancy-validated cooperative grid: query once, cache. Never exceed
  // what the runtime will accept (round-6 failure: hand-computed 7/CU grid
  // was rejected -> kernel never ran). Kernel is grid-stride correct for any
  // grid that is a multiple of 8 blocks.
  static int blocks_per_cu = 0;
  if (blocks_per_cu == 0) {
    int n = 0;
    hipError_t e = hipOccupancyMaxActiveBlocksPerMultiprocessor(
        &n, (const void*)mega_kernel, 256, 0);
    blocks_per_cu = (e == hipSuccess && n > 0) ? n : 2;
    if (blocks_per_cu > 8) blocks_per_cu = 8;
  }
  const int grid = blocks_per_cu * 256;  // 256 CUs; multiple of 8

  void* args[] = {(void*)&x4,     (void*)&bbox,   (void*)&src,
                  (void*)&dst,    (void*)&W1rel,  (void*)&b1,
                  (void*)&W1root, (void*)&W2rel,  (void*)&b2,
                  (void*)&W2root, (void*)&is_bbox_bits,
                  (void*)&needed_bits, (void*)&cnt, (void*)&qcnt,
                  (void*)&qseg,   (void*)&slots,  (void*)&xb,
                  (void*)&hb,     (void*)&wf,     (void*)&out};
  hipLaunchCooperativeKernel((const void*)mega_kernel, dim3(grid), dim3(256),
                             args, 0, stream);
}

// Round 9
// 193.155 us; speedup vs baseline: 2.8392x; 2.8392x over previous
//
#include <hip/hip_runtime.h>

#define N_NODES 100000
#define N_EDGES 1600000
#define D 64
#define N_BBOX 4096
#define CAP 64       // per-node slot capacity; deg ~ Poisson(16), P(>=64) ~ 1e-20
#define NBITW 3136   // words for N_NODES bits, padded
#define NTILE1 (N_NODES / 16)  // 6250
#define NTILE2 (N_BBOX / 16)   // 256

typedef short bf16x8 __attribute__((ext_vector_type(8)));
typedef float f32x4 __attribute__((ext_vector_type(4)));

__device__ __forceinline__ int bperm(int srclane, int v) {
  return __builtin_amdgcn_ds_bpermute(srclane << 2, v);
}
__device__ __forceinline__ float lrelu(float v) {
  return fmaxf(v, 0.01f * v);  // neg_slope 0.01 > 0
}
__device__ __forceinline__ bool testbit(const unsigned* bits, int i) {
  return (bits[i >> 5] >> (i & 31)) & 1u;
}
__device__ __forceinline__ short f2bf(float f) {  // RNE fp32 -> bf16
  unsigned u = __float_as_uint(f);
  u += 0x7FFFu + ((u >> 16) & 1u);
  return (short)(u >> 16);
}

// ---- kernel 1: bbox marking (after memset of the two bitmasks) ----
__global__ __launch_bounds__(256) void mark_bbox_kernel(
    const int* __restrict__ bbox, unsigned* __restrict__ is_bbox_bits,
    unsigned* __restrict__ needed_bits) {
  const int t = blockIdx.x * 256 + threadIdx.x;  // grid covers N_BBOX exactly
  const int n = bbox[t];
  const unsigned m = 1u << (n & 31);
  atomicOr(&is_bbox_bits[n >> 5], m);
  atomicOr(&needed_bits[n >> 5], m);
}

// ---- kernel 2: fused xprep (x->bf16) + cnt zero + W frag pack + edge mark ----
// Weight fragment table (fragment-major bf16): for layer l, mat m (0=rel,1=root),
// kh, quad, col, i: wf[l*8192 + m*4096 + kh*2048 + quad*512 + col*8 + i]
//   = bf16(W[k*64 + col]), k = kh*32 + quad*8 + i.
// Edge-mark: needed |= {src of edges whose dst is bbox} (is_bbox complete).
__global__ __launch_bounds__(256) void prep_kernel(const float4* __restrict__ x4,
                                                   bf16x8* __restrict__ xb,
                                                   const int* __restrict__ src,
                                                   const int* __restrict__ dst,
                                                   const unsigned* __restrict__ is_bbox_bits,
                                                   unsigned* __restrict__ needed_bits,
                                                   int* __restrict__ cnt,
                                                   const float* __restrict__ W1rel,
                                                   const float* __restrict__ W1root,
                                                   const float* __restrict__ W2rel,
                                                   const float* __restrict__ W2root,
                                                   short* __restrict__ wf) {
  const int i = blockIdx.x * 256 + threadIdx.x;
  if (i < N_NODES) cnt[i] = 0;
  if (i < N_NODES * 8) {  // one 8-elem chunk per thread
    const float4 a = x4[i * 2], b = x4[i * 2 + 1];
    bf16x8 r;
    r[0] = f2bf(a.x); r[1] = f2bf(a.y); r[2] = f2bf(a.z); r[3] = f2bf(a.w);
    r[4] = f2bf(b.x); r[5] = f2bf(b.y); r[6] = f2bf(b.z); r[7] = f2bf(b.w);
    xb[i] = r;
  } else {
    const int t = i - N_NODES * 8;
    if (t < 4 * 4096) {  // weight fragment pack
      const int layer = t >> 13;           // 0: W1, 1: W2
      const int r = t & 8191;
      const int m = r >> 12;               // 0: rel, 1: root
      const int e = r & 4095;
      const int kh = e >> 11, quad = (e >> 9) & 3;
      const int col = (e >> 3) & 63, ii = e & 7;
      const int k = kh * 32 + quad * 8 + ii;
      const float* W = layer ? (m ? W2root : W2rel) : (m ? W1root : W1rel);
      wf[t] = f2bf(W[k * 64 + col]);
    } else {
      const int e = t - 4 * 4096;          // edge mark, [0, N_EDGES)
      if (e < N_EDGES) {
        if (testbit(is_bbox_bits, dst[e]))  // ~4%; bitmask L1/L2-hot
          atomicOr(&needed_bits[src[e] >> 5], 1u << (src[e] & 31));
      }
    }
  }
}

// ---- kernel 3: direct slot scatter (replaces scan+scatterB; no qseg) ----
// Slot order within a node is atomic-race-ordered: only changes fp32 add
// order of <=64 bf16 terms (within test tolerance).
__global__ __launch_bounds__(256) void scatter_kernel(
    const int* __restrict__ src, const int* __restrict__ dst,
    const unsigned* __restrict__ needed_bits, int* __restrict__ cnt,
    int* __restrict__ slots) {
  const int e = blockIdx.x * 256 + threadIdx.x;  // grid covers N_EDGES exactly
  const int d = dst[e];
  if (!testbit(needed_bits, d)) return;  // ~50% discard
  const int s = src[e];
  const int pos = atomicAdd(&cnt[d], 1);
  if (pos < CAP) slots[(size_t)d * CAP + pos] = s;
}

// ---- wave-cooperative gather-sum (round-3 verified): 4-deep batches,
// wave-uniform skip of dead sub-batches. On exit accf[i] of lane (g=0,c)
// holds element c*8+i of the row-sum, replicated across 8 groups.
__device__ __forceinline__ void gather_rows(const uint4* __restrict__ rows,
                                            const int* __restrict__ slots,
                                            int node, int n, int lane,
                                            float accf[8]) {
  const int g = lane >> 3, c = lane & 7;
  const int myslot = (lane < n) ? slots[(size_t)node * CAP + lane] : 0;
#pragma unroll
  for (int i = 0; i < 8; i++) accf[i] = 0.f;
  for (int e0 = 0; e0 < n; e0 += 32) {
    const int rem = n - e0;  // wave-uniform
    int idx[4], s[4];
    uint4 v[4];
#pragma unroll
    for (int u = 0; u < 4; u++)
      if (u * 8 < rem) {
        idx[u] = e0 + u * 8 + g;
        s[u] = bperm(idx[u], myslot);
      }
#pragma unroll
    for (int u = 0; u < 4; u++)
      if (u * 8 < rem) {
        v[u] = make_uint4(0u, 0u, 0u, 0u);
        if (idx[u] < n) v[u] = rows[(size_t)s[u] * 8 + c];
      }
#pragma unroll
    for (int u = 0; u < 4; u++)
      if (u * 8 < rem) {
        accf[0] += __uint_as_float(v[u].x << 16);
        accf[1] += __uint_as_float(v[u].x & 0xFFFF0000u);
        accf[2] += __uint_as_float(v[u].y << 16);
        accf[3] += __uint_as_float(v[u].y & 0xFFFF0000u);
        accf[4] += __uint_as_float(v[u].z << 16);
        accf[5] += __uint_as_float(v[u].z & 0xFFFF0000u);
        accf[6] += __uint_as_float(v[u].w << 16);
        accf[7] += __uint_as_float(v[u].w & 0xFFFF0000u);
      }
  }
#pragma unroll
  for (int off = 8; off < 64; off <<= 1)
#pragma unroll
    for (int i = 0; i < 8; i++) accf[i] += __shfl_xor(accf[i], off);
}

// ---- kernel 4: layer-1 gather -> LDS -> ONE barrier -> MFMA -> hb ----
// ONE tile per block (grid 6250 = 24 blocks/CU queued): drain-tail smoothing
// vs round-3's 1.5 residency rounds. Wave wid gathers rows wid*4..+3, then
// computes column-quadrant wid of the same tile.
__global__ __launch_bounds__(256) void gd1_kernel(
    const uint4* __restrict__ xb4, const short* __restrict__ xb,
    const unsigned* __restrict__ needed_bits, const int* __restrict__ cnt,
    const int* __restrict__ slots, const short* __restrict__ wf1,
    const float* __restrict__ b1, short* __restrict__ hb) {
  __shared__ __align__(16) short aggt[16][72];
  const int t = threadIdx.x;
  const int lane = t & 63;
  const int wid = t >> 6;  // 0..3 = wave id = nt quadrant
  const int cn = lane & 15, quad = lane >> 4;
  const int col = wid * 16 + cn;
  const int node0 = blockIdx.x * 16;  // grid == NTILE1 exactly

  const bf16x8* wfv = (const bf16x8*)wf1;
  bf16x8 brel[2], broot[2];
#pragma unroll
  for (int kh = 0; kh < 2; kh++) {
    brel[kh] = wfv[(kh * 4 + quad) * 64 + col];
    broot[kh] = wfv[((2 + kh) * 4 + quad) * 64 + col];
  }
  const float bj = b1[col];

#pragma unroll
  for (int r4 = 0; r4 < 4; r4++) {
    const int row = wid * 4 + r4;
    const int node = node0 + row;
    int n = cnt[node];
    n = (n > CAP) ? CAP : n;
    if (n == 0) {  // non-needed (filtered) or deg-0: zero row
      if (lane < 8) {
        bf16x8 z = {0, 0, 0, 0, 0, 0, 0, 0};
        *(bf16x8*)(&aggt[row][lane * 8]) = z;
      }
      continue;
    }
    float accf[8];
    gather_rows(xb4, slots, node, n, lane, accf);
    if (lane < 8) {
      bf16x8 r;
#pragma unroll
      for (int i = 0; i < 8; i++) r[i] = f2bf(accf[i]);
      *(bf16x8*)(&aggt[row][lane * 8]) = r;
    }
  }
  __syncthreads();  // the only barrier

  const int mrow = node0 + cn;
  const bool ndrow = testbit(needed_bits, mrow);
  f32x4 acc = {};
#pragma unroll
  for (int kh = 0; kh < 2; kh++) {
    const bf16x8 a_agg = *(const bf16x8*)(&aggt[cn][kh * 32 + quad * 8]);
    bf16x8 a_x = {0, 0, 0, 0, 0, 0, 0, 0};
    if (ndrow)
      a_x = *(const bf16x8*)(xb + (size_t)mrow * D + kh * 32 + quad * 8);
    acc = __builtin_amdgcn_mfma_f32_16x16x32_bf16(a_agg, brel[kh], acc, 0, 0, 0);
    acc = __builtin_amdgcn_mfma_f32_16x16x32_bf16(a_x, broot[kh], acc, 0, 0, 0);
  }
#pragma unroll
  for (int r = 0; r < 4; r++) {
    const int row = quad * 4 + r;
    if (testbit(needed_bits, node0 + row))
      hb[(size_t)(node0 + row) * D + col] = f2bf(lrelu(acc[r] + bj));
  }
}

// ---- kernel 5: layer-2 for bbox rows ----
__global__ __launch_bounds__(256) void gd2_kernel(
    const uint4* __restrict__ hb4, const short* __restrict__ hb,
    const int* __restrict__ cnt, const int* __restrict__ slots,
    const int* __restrict__ bbox, const short* __restrict__ wf2,
    const float* __restrict__ b2, float* __restrict__ out) {
  __shared__ __align__(16) short aggt[16][72];
  __shared__ int nodes_s[16];
  const int t = threadIdx.x;
  const int lane = t & 63;
  const int wid = t >> 6;
  const int cn = lane & 15, quad = lane >> 4;
  const int col = wid * 16 + cn;
  const int t0 = blockIdx.x * 16;  // grid = NTILE2 exactly

  if (t < 16) nodes_s[t] = bbox[t0 + t];

  const bf16x8* wfv = (const bf16x8*)wf2;
  bf16x8 brel[2], broot[2];
#pragma unroll
  for (int kh = 0; kh < 2; kh++) {
    brel[kh] = wfv[(kh * 4 + quad) * 64 + col];
    broot[kh] = wfv[((2 + kh) * 4 + quad) * 64 + col];
  }
  const float bj = b2[col];
  __syncthreads();

#pragma unroll
  for (int r4 = 0; r4 < 4; r4++) {
    const int row = wid * 4 + r4;
    const int node = nodes_s[row];
    int n = cnt[node];
    n = (n > CAP) ? CAP : n;
    if (n == 0) {
      if (lane < 8) {
        bf16x8 z = {0, 0, 0, 0, 0, 0, 0, 0};
        *(bf16x8*)(&aggt[row][lane * 8]) = z;
      }
      continue;
    }
    float accf[8];
    gather_rows(hb4, slots, node, n, lane, accf);
    if (lane < 8) {
      bf16x8 r;
#pragma unroll
      for (int i = 0; i < 8; i++) r[i] = f2bf(accf[i]);
      *(bf16x8*)(&aggt[row][lane * 8]) = r;
    }
  }
  __syncthreads();

  const int rnode = nodes_s[cn];  // root row for A[m=cn]
  f32x4 acc = {};
#pragma unroll
  for (int kh = 0; kh < 2; kh++) {
    const bf16x8 a_agg = *(const bf16x8*)(&aggt[cn][kh * 32 + quad * 8]);
    const bf16x8 a_h = *(const bf16x8*)(hb + (size_t)rnode * D + kh * 32 + quad * 8);
    acc = __builtin_amdgcn_mfma_f32_16x16x32_bf16(a_agg, brel[kh], acc, 0, 0, 0);
    acc = __builtin_amdgcn_mfma_f32_16x16x32_bf16(a_h, broot[kh], acc, 0, 0, 0);
  }
#pragma unroll
  for (int r = 0; r < 4; r++) {
    const int row = quad * 4 + r;
    out[(size_t)(t0 + row) * D + col] = lrelu(acc[r] + bj);
  }
}

// ---------------- launch ----------------

extern "C" void kernel_launch(void* const* d_in, const int* in_sizes, int n_in,
                              void* d_out, int out_size, void* d_ws, size_t ws_size,
                              hipStream_t stream) {
  const float* x = (const float*)d_in[0];
  const int* ei = (const int*)d_in[1];
  const int* src = ei;
  const int* dst = ei + N_EDGES;
  const int* bbox = (const int*)d_in[2];
  const float* W1rel = (const float*)d_in[3];
  const float* b1 = (const float*)d_in[4];
  const float* W1root = (const float*)d_in[5];
  const float* W2rel = (const float*)d_in[6];
  const float* b2 = (const float*)d_in[7];
  const float* W2root = (const float*)d_in[8];
  float* out = (float*)d_out;

  char* ws = (char*)d_ws;
  size_t off = 0;
  auto alloc = [&](size_t bytes) -> char* {
    char* p = ws + off;
    off = (off + bytes + 511) & ~(size_t)511;
    return p;
  };
  // contiguous zero region: just the two bitmasks (25 KB); cnt zeroed in prep
  unsigned* is_bbox_bits = (unsigned*)alloc(NBITW * sizeof(unsigned));
  unsigned* needed_bits = (unsigned*)alloc(NBITW * sizeof(unsigned));
  char* zero_end = ws + off;
  int* cnt = (int*)alloc(N_NODES * sizeof(int));
  int* slots = (int*)alloc((size_t)N_NODES * CAP * sizeof(int));          // 25.6 MB
  short* xb = (short*)alloc((size_t)N_NODES * D * sizeof(short));         // 12.8 MB
  short* hb = (short*)alloc((size_t)N_NODES * D * sizeof(short));         // 12.8 MB
  short* wf = (short*)alloc((size_t)4 * 4096 * sizeof(short));            // 32 KB

  hipMemsetAsync(is_bbox_bits, 0, (size_t)(zero_end - (char*)is_bbox_bits), stream);
  mark_bbox_kernel<<<N_BBOX / 256, 256, 0, stream>>>(bbox, is_bbox_bits,
                                                     needed_bits);
  prep_kernel<<<(N_NODES * 8 + 4 * 4096 + N_EDGES + 255) / 256, 256, 0, stream>>>(
      (const float4*)x, (bf16x8*)xb, src, dst, is_bbox_bits, needed_bits, cnt,
      W1rel, W1root, W2rel, W2root, wf);
  scatter_kernel<<<N_EDGES / 256, 256, 0, stream>>>(src, dst, needed_bits, cnt,
                                                    slots);
  gd1_kernel<<<NTILE1, 256, 0, stream>>>((const uint4*)xb, xb, needed_bits, cnt,
                                         slots, wf, b1, hb);
  gd2_kernel<<<NTILE2, 256, 0, stream>>>((const uint4*)hb, hb, cnt, slots, bbox,
                                         wf + 8192, b2, out);
}